// Round 14
// baseline (48.373 us; speedup 1.0000x reference)
//
#include <hip/hip_runtime.h>

#define K7   7
#define PAD3 3
#define C64  64
#define CRED 32          // C/2
#define GC4  4
#define EPSV 1e-5f

#define TILE 8                      // 8x8 pixels per block (k2 / fused)
#define HALO 14                     // TILE + K7 - 1
#define NPIX (HALO * HALO)          // 196

typedef _Float16 half8 __attribute__((ext_vector_type(8)));
typedef _Float16 half4 __attribute__((ext_vector_type(4)));
typedef float    f32x4 __attribute__((ext_vector_type(4)));

// ============================= two-kernel path =============================
// ---- kernel 1: conv1 (1x1) + BN(eval) + ReLU -> t[b][pix][32] as f16 ----
__global__ __launch_bounds__(256, 4)
void conv1_bn_relu(const float* __restrict__ x,  const float* __restrict__ w1,
                   const float* __restrict__ b1, const float* __restrict__ gma,
                   const float* __restrict__ bta, const float* __restrict__ mu,
                   const float* __restrict__ var, _Float16* __restrict__ t)
{
    const int tid = threadIdx.x;
    const int p   = tid & 63;
    const int oq  = __builtin_amdgcn_readfirstlane(tid >> 6);
    const int task = blockIdx.x * 64 + p;           // 0 .. 65535
    const int b   = task >> 14;
    const int pix = task & 16383;

    float dot[8] = {0,0,0,0,0,0,0,0};
    const float* w1q = w1 + oq * 8 * C64;
    const float* xp  = x + ((size_t)b << 20) + pix;
    #pragma unroll 8
    for (int c = 0; c < C64; ++c) {
        float xc = xp[(size_t)c << 14];
        #pragma unroll
        for (int j = 0; j < 8; ++j) dot[j] += w1q[j * C64 + c] * xc;
    }
    _Float16 tv[8];
    #pragma unroll
    for (int j = 0; j < 8; ++j) {
        int o = oq * 8 + j;
        float sv = gma[o] * rsqrtf(var[o] + EPSV);
        float bb = (b1[o] - mu[o]) * sv + bta[o];
        tv[j] = (_Float16)fmaxf(dot[j] * sv + bb, 0.f);
    }
    *(half8*)&t[((size_t)((b << 14) + pix)) * 32 + oq * 8] = *(const half8*)tv;
}

// ---- kernel 2: per-pixel dynamic kernels (MFMA) + depthwise aggregation ----
// Half-channel blocks: 32 y-channels, 8 groups, 4 waves x 2 groups per wave.
#define NSLH 8                      // groups per block
#define YPS  40                     // ytile per-pixel stride in f16 (80B):
                                    // byte step 80 -> bank step 20, conflict-free
#define W2ST 40                     // w2h row stride in f16
#define W2G  (49 * W2ST)            // 1960 f16 per group

__global__ __launch_bounds__(256, 2)
void invol_agg(const float* __restrict__ y, const _Float16* __restrict__ t,
               const float* __restrict__ w2, const float* __restrict__ b2,
               float* __restrict__ out)
{
    __shared__ __align__(16) _Float16 ytile[NPIX * YPS];   // 15680 B
    __shared__ __align__(16) _Float16 w2h[NSLH * W2G];     // 31360 B

    const int tid = threadIdx.x;
    // XCD-aware swizzle: 2048 blocks -> 8 chunks of 256 contiguous tiles
    const int wgid = blockIdx.x + (blockIdx.y << 4) + (blockIdx.z << 8);
    const int swz  = ((wgid & 7) << 8) | (wgid >> 3);
    const int bx = swz & 15, by = (swz >> 4) & 15, bz = swz >> 8;  // bz 0..7
    const int b = bz >> 1, half = bz & 1;
    const int gh0 = by * TILE, gw0 = bx * TILE;
    const int c0 = half * 32;

    const int p  = tid & 63;
    const int ph = p >> 3, pw = p & 7;
    const int oq = __builtin_amdgcn_readfirstlane(tid >> 6);  // wave 0..3
    const int q  = p >> 4, r = p & 15;
    const int pix = ((gh0 + ph) << 7) + (gw0 + pw);

    // --- issue B-fragment loads EARLY: latency hides under LDS staging ---
    const _Float16* tb = t + ((size_t)(b << 14)) * 32;
    const int rr8 = r >> 3, rc = r & 7;
    half8 bfrag0 = *(const half8*)&tb[(size_t)(((gh0 + 0 + rr8) << 7) + gw0 + rc) * 32 + q * 8];
    half8 bfrag1 = *(const half8*)&tb[(size_t)(((gh0 + 2 + rr8) << 7) + gw0 + rc) * 32 + q * 8];
    half8 bfrag2 = *(const half8*)&tb[(size_t)(((gh0 + 4 + rr8) << 7) + gw0 + rc) * 32 + q * 8];
    half8 bfrag3 = *(const half8*)&tb[(size_t)(((gh0 + 6 + rr8) << 7) + gw0 + rc) * 32 + q * 8];

    // --- stage y halo as f16: 32 channels, 8 cg groups ---
    for (int u = tid; u < 8 * NPIX; u += 256) {
        int cg   = u / NPIX;                 // channel-group 0..7
        int pixl = u - cg * NPIX;
        int rr   = pixl / HALO;
        int col  = pixl - rr * HALO;
        int grow = gh0 - PAD3 + rr;
        int gcol = gw0 - PAD3 + col;
        half4 v = {(_Float16)0.f, (_Float16)0.f, (_Float16)0.f, (_Float16)0.f};
        if ((unsigned)grow < 128u && (unsigned)gcol < 128u) {
            const float* yp = y + ((size_t)(b * C64 + c0 + cg * 4) << 14) + (grow << 7) + gcol;
            v[0] = (_Float16)yp[0];
            v[1] = (_Float16)yp[1 << 14];
            v[2] = (_Float16)yp[2 << 14];
            v[3] = (_Float16)yp[3 << 14];
        }
        *(half4*)&ytile[pixl * YPS + cg * 4] = v;
    }

    // --- stage w2 (this block's 8 groups) as f16 [lg][49 x stride 40] ---
    for (int u = tid; u < NSLH * 49 * 8; u += 256) {     // 3136 half4-units
        int lg  = u / 392;                   // 49*8
        int rem = u - lg * 392;
        int row = rem >> 3;
        int k4  = (rem & 7) << 2;
        const float4 w4 = *(const float4*)&w2[(((half * NSLH + lg) * 49 + row) << 5) + k4];
        half4 h;
        h[0] = (_Float16)w4.x; h[1] = (_Float16)w4.y;
        h[2] = (_Float16)w4.z; h[3] = (_Float16)w4.w;
        *(half4*)&w2h[lg * W2G + row * W2ST + k4] = h;
    }
    __syncthreads();

    // per-lane f16-index bases into ytile: tp2*YPS + oq*8 (8 channels = 2 groups)
    const int pbF0 = ((0 + rr8) * HALO + rc) * YPS + oq * 8;
    const int pbF1 = ((2 + rr8) * HALO + rc) * YPS + oq * 8;
    const int pbF2 = ((4 + rr8) * HALO + rc) * YPS + oq * 8;
    const int pbF3 = ((6 + rr8) * HALO + rc) * YPS + oq * 8;

    const f32x4 zero = {0.f, 0.f, 0.f, 0.f};

    const int lg0 = 2 * oq, lg1 = 2 * oq + 1;      // this wave's two groups
    const int g0  = half * NSLH + lg0;             // global group (g1 = g0+1)
    const float* b2g0 = b2 + g0 * 49;
    const float* b2g1 = b2 + (g0 + 1) * 49;
    const _Float16* w2hg0 = w2h + lg0 * W2G;       // wave-uniform bases
    const _Float16* w2hg1 = w2h + lg1 * W2G;

    float acc0[4][4], acc1[4][4];
    #pragma unroll
    for (int nt = 0; nt < 4; ++nt)
        #pragma unroll
        for (int c = 0; c < 4; ++c) { acc0[nt][c] = 0.f; acc1[nt][c] = 0.f; }

    // mt = 0..2 : rolled (liveness cap); two interleaved group streams
    #pragma clang loop unroll(disable)
    for (int mt = 0; mt < 3; ++mt) {
        const half8 af0 = *(const half8*)&w2hg0[(mt * 16 + r) * W2ST + q * 8];
        const half8 af1 = *(const half8*)&w2hg1[(mt * 16 + r) * W2ST + q * 8];
        const int bi = mt * 16 + q * 4;
        const f32x4 cb0 = { b2g0[bi+0], b2g0[bi+1], b2g0[bi+2], b2g0[bi+3] };
        const f32x4 cb1 = { b2g1[bi+0], b2g1[bi+1], b2g1[bi+2], b2g1[bi+3] };

        f32x4 d0 = __builtin_amdgcn_mfma_f32_16x16x32_f16(af0, bfrag0, cb0, 0, 0, 0);
        f32x4 d1 = __builtin_amdgcn_mfma_f32_16x16x32_f16(af0, bfrag1, cb0, 0, 0, 0);
        f32x4 d2 = __builtin_amdgcn_mfma_f32_16x16x32_f16(af0, bfrag2, cb0, 0, 0, 0);
        f32x4 d3 = __builtin_amdgcn_mfma_f32_16x16x32_f16(af0, bfrag3, cb0, 0, 0, 0);
        f32x4 e0 = __builtin_amdgcn_mfma_f32_16x16x32_f16(af1, bfrag0, cb1, 0, 0, 0);
        f32x4 e1 = __builtin_amdgcn_mfma_f32_16x16x32_f16(af1, bfrag1, cb1, 0, 0, 0);
        f32x4 e2 = __builtin_amdgcn_mfma_f32_16x16x32_f16(af1, bfrag2, cb1, 0, 0, 0);
        f32x4 e3 = __builtin_amdgcn_mfma_f32_16x16x32_f16(af1, bfrag3, cb1, 0, 0, 0);

        #pragma unroll
        for (int reg = 0; reg < 4; ++reg) {          // MUST stay fully unrolled
            const int tap = mt * 16 + q * 4 + reg;   // lane's tap, < 49
            const int di = (tap * 9363) >> 16;       // tap / 7
            const int toffF = (tap + 7 * di) * YPS;  // (di*14 + dj) * YPS
            {
                const half8 y8 = *(const half8*)&ytile[pbF0 + toffF];
                const float wv = d0[reg], ev = e0[reg];
                acc0[0][0] += (float)y8[0] * wv; acc0[0][1] += (float)y8[1] * wv;
                acc0[0][2] += (float)y8[2] * wv; acc0[0][3] += (float)y8[3] * wv;
                acc1[0][0] += (float)y8[4] * ev; acc1[0][1] += (float)y8[5] * ev;
                acc1[0][2] += (float)y8[6] * ev; acc1[0][3] += (float)y8[7] * ev;
            }
            {
                const half8 y8 = *(const half8*)&ytile[pbF1 + toffF];
                const float wv = d1[reg], ev = e1[reg];
                acc0[1][0] += (float)y8[0] * wv; acc0[1][1] += (float)y8[1] * wv;
                acc0[1][2] += (float)y8[2] * wv; acc0[1][3] += (float)y8[3] * wv;
                acc1[1][0] += (float)y8[4] * ev; acc1[1][1] += (float)y8[5] * ev;
                acc1[1][2] += (float)y8[6] * ev; acc1[1][3] += (float)y8[7] * ev;
            }
            {
                const half8 y8 = *(const half8*)&ytile[pbF2 + toffF];
                const float wv = d2[reg], ev = e2[reg];
                acc0[2][0] += (float)y8[0] * wv; acc0[2][1] += (float)y8[1] * wv;
                acc0[2][2] += (float)y8[2] * wv; acc0[2][3] += (float)y8[3] * wv;
                acc1[2][0] += (float)y8[4] * ev; acc1[2][1] += (float)y8[5] * ev;
                acc1[2][2] += (float)y8[6] * ev; acc1[2][3] += (float)y8[7] * ev;
            }
            {
                const half8 y8 = *(const half8*)&ytile[pbF3 + toffF];
                const float wv = d3[reg], ev = e3[reg];
                acc0[3][0] += (float)y8[0] * wv; acc0[3][1] += (float)y8[1] * wv;
                acc0[3][2] += (float)y8[2] * wv; acc0[3][3] += (float)y8[3] * wv;
                acc1[3][0] += (float)y8[4] * ev; acc1[3][1] += (float)y8[5] * ev;
                acc1[3][2] += (float)y8[6] * ev; acc1[3][3] += (float)y8[7] * ev;
            }
        }
    }

    // mt = 3 : only tap 48 real (lane r==0 holds row 48; q==0 output)
    {
        half8 af0 = *(const half8*)&w2hg0[48 * W2ST + q * 8];
        half8 af1 = *(const half8*)&w2hg1[48 * W2ST + q * 8];
        if (r != 0) {
            #pragma unroll
            for (int j = 0; j < 8; ++j) { af0[j] = (_Float16)0.f; af1[j] = (_Float16)0.f; }
        }
        f32x4 d0 = __builtin_amdgcn_mfma_f32_16x16x32_f16(af0, bfrag0, zero, 0, 0, 0);
        f32x4 d1 = __builtin_amdgcn_mfma_f32_16x16x32_f16(af0, bfrag1, zero, 0, 0, 0);
        f32x4 d2 = __builtin_amdgcn_mfma_f32_16x16x32_f16(af0, bfrag2, zero, 0, 0, 0);
        f32x4 d3 = __builtin_amdgcn_mfma_f32_16x16x32_f16(af0, bfrag3, zero, 0, 0, 0);
        f32x4 e0 = __builtin_amdgcn_mfma_f32_16x16x32_f16(af1, bfrag0, zero, 0, 0, 0);
        f32x4 e1 = __builtin_amdgcn_mfma_f32_16x16x32_f16(af1, bfrag1, zero, 0, 0, 0);
        f32x4 e2 = __builtin_amdgcn_mfma_f32_16x16x32_f16(af1, bfrag2, zero, 0, 0, 0);
        f32x4 e3 = __builtin_amdgcn_mfma_f32_16x16x32_f16(af1, bfrag3, zero, 0, 0, 0);

        const float bv0 = b2g0[48], bv1 = b2g1[48];
        const int toffF = (48 + 7 * 6) * YPS;        // 90*YPS, uniform
        const bool live = (q == 0);
        {
            const half8 y8 = *(const half8*)&ytile[pbF0 + toffF];
            float wv = live ? (d0[0] + bv0) : 0.f;
            float ev = live ? (e0[0] + bv1) : 0.f;
            acc0[0][0] += (float)y8[0] * wv; acc0[0][1] += (float)y8[1] * wv;
            acc0[0][2] += (float)y8[2] * wv; acc0[0][3] += (float)y8[3] * wv;
            acc1[0][0] += (float)y8[4] * ev; acc1[0][1] += (float)y8[5] * ev;
            acc1[0][2] += (float)y8[6] * ev; acc1[0][3] += (float)y8[7] * ev;
        }
        {
            const half8 y8 = *(const half8*)&ytile[pbF1 + toffF];
            float wv = live ? (d1[0] + bv0) : 0.f;
            float ev = live ? (e1[0] + bv1) : 0.f;
            acc0[1][0] += (float)y8[0] * wv; acc0[1][1] += (float)y8[1] * wv;
            acc0[1][2] += (float)y8[2] * wv; acc0[1][3] += (float)y8[3] * wv;
            acc1[1][0] += (float)y8[4] * ev; acc1[1][1] += (float)y8[5] * ev;
            acc1[1][2] += (float)y8[6] * ev; acc1[1][3] += (float)y8[7] * ev;
        }
        {
            const half8 y8 = *(const half8*)&ytile[pbF2 + toffF];
            float wv = live ? (d2[0] + bv0) : 0.f;
            float ev = live ? (e2[0] + bv1) : 0.f;
            acc0[2][0] += (float)y8[0] * wv; acc0[2][1] += (float)y8[1] * wv;
            acc0[2][2] += (float)y8[2] * wv; acc0[2][3] += (float)y8[3] * wv;
            acc1[2][0] += (float)y8[4] * ev; acc1[2][1] += (float)y8[5] * ev;
            acc1[2][2] += (float)y8[6] * ev; acc1[2][3] += (float)y8[7] * ev;
        }
        {
            const half8 y8 = *(const half8*)&ytile[pbF3 + toffF];
            float wv = live ? (d3[0] + bv0) : 0.f;
            float ev = live ? (e3[0] + bv1) : 0.f;
            acc0[3][0] += (float)y8[0] * wv; acc0[3][1] += (float)y8[1] * wv;
            acc0[3][2] += (float)y8[2] * wv; acc0[3][3] += (float)y8[3] * wv;
            acc1[3][0] += (float)y8[4] * ev; acc1[3][1] += (float)y8[5] * ev;
            acc1[3][2] += (float)y8[6] * ev; acc1[3][3] += (float)y8[7] * ev;
        }
    }

    #pragma unroll
    for (int nt = 0; nt < 4; ++nt)
        #pragma unroll
        for (int c = 0; c < 4; ++c) {
            float v0 = acc0[nt][c];
            v0 += __shfl_xor(v0, 16);
            v0 += __shfl_xor(v0, 32);
            acc0[nt][c] = v0;
            float v1 = acc1[nt][c];
            v1 += __shfl_xor(v1, 16);
            v1 += __shfl_xor(v1, 32);
            acc1[nt][c] = v1;
        }

    // lane p stores pixel p; 8 output channels (2 groups)
    size_t ob = ((size_t)(b * C64 + g0 * GC4) << 14) + pix;
    #pragma unroll
    for (int c = 0; c < 4; ++c) {
        float s0 = (q & 1) ? acc0[1][c] : acc0[0][c];
        float s1 = (q & 1) ? acc0[3][c] : acc0[2][c];
        out[ob + ((size_t)c << 14)] = (q & 2) ? s1 : s0;
    }
    #pragma unroll
    for (int c = 0; c < 4; ++c) {
        float s0 = (q & 1) ? acc1[1][c] : acc1[0][c];
        float s1 = (q & 1) ? acc1[3][c] : acc1[2][c];
        out[ob + ((size_t)(c + 4) << 14)] = (q & 2) ? s1 : s0;
    }
}

// ======================= fused fallback (round-6, 60.8µs) =======================
#define NCHF 32
#define NSLF 8
#define TSTH 40

__global__ __launch_bounds__(256, 2)
void involution_fused_fb(const float* __restrict__ x, const float* __restrict__ y,
                         const float* __restrict__ w1, const float* __restrict__ b1,
                         const float* __restrict__ gma, const float* __restrict__ bta,
                         const float* __restrict__ mu,  const float* __restrict__ var,
                         const float* __restrict__ w2,  const float* __restrict__ b2,
                         float* __restrict__ out)
{
    __shared__ __align__(16) float    ytile[NPIX * NCHF];
    __shared__ __align__(16) _Float16 t_lds[64 * TSTH];

    const int tid = threadIdx.x;
    const int bx = blockIdx.x, by = blockIdx.y, bz = blockIdx.z;
    const int b = bz >> 1, half = bz & 1;
    const int gh0 = by * TILE, gw0 = bx * TILE;
    const int c0 = half * NCHF;

    for (int li = tid; li < NCHF * NPIX; li += 256) {
        int c    = li / NPIX;
        int pixl = li - c * NPIX;
        int rr   = pixl / HALO;
        int col  = pixl - rr * HALO;
        int grow = gh0 - PAD3 + rr;
        int gcol = gw0 - PAD3 + col;
        float v = 0.f;
        if ((unsigned)grow < 128u && (unsigned)gcol < 128u)
            v = y[((size_t)(b * C64 + c0 + c) << 14) + (grow << 7) + gcol];
        int slot = ((c >> 2) + pixl) & 7;
        ytile[pixl * NCHF + slot * 4 + (c & 3)] = v;
    }

    const int p  = tid & 63;
    const int ph = p >> 3, pw = p & 7;
    const int oq = __builtin_amdgcn_readfirstlane(tid >> 6);
    const int pix = ((gh0 + ph) << 7) + (gw0 + pw);
    {
        float dot[8] = {0,0,0,0,0,0,0,0};
        const float* w1q = w1 + oq * 8 * C64;
        const float* xp  = x + ((size_t)(b * C64) << 14) + pix;
        #pragma unroll 8
        for (int c = 0; c < C64; ++c) {
            float xc = xp[(size_t)c << 14];
            #pragma unroll
            for (int j = 0; j < 8; ++j) dot[j] += w1q[j * C64 + c] * xc;
        }
        _Float16 tv16[8];
        #pragma unroll
        for (int j = 0; j < 8; ++j) {
            int o = oq * 8 + j;
            float sv = gma[o] * rsqrtf(var[o] + EPSV);
            float bb = (b1[o] - mu[o]) * sv + bta[o];
            tv16[j] = (_Float16)fmaxf(dot[j] * sv + bb, 0.f);
        }
        *(half8*)&t_lds[p * TSTH + oq * 8] = *(const half8*)tv16;
    }
    __syncthreads();

    const int q = p >> 4;
    const int r = p & 15;

    half8 bfrag0 = *(const half8*)&t_lds[( 0 + r) * TSTH + q * 8];
    half8 bfrag1 = *(const half8*)&t_lds[(16 + r) * TSTH + q * 8];
    half8 bfrag2 = *(const half8*)&t_lds[(32 + r) * TSTH + q * 8];
    half8 bfrag3 = *(const half8*)&t_lds[(48 + r) * TSTH + q * 8];

    const int pb0 = (0 + (r >> 3)) * HALO + (r & 7);
    const int pb1 = (2 + (r >> 3)) * HALO + (r & 7);
    const int pb2 = (4 + (r >> 3)) * HALO + (r & 7);
    const int pb3 = (6 + (r >> 3)) * HALO + (r & 7);

    const f32x4 zero = {0.f, 0.f, 0.f, 0.f};

    #pragma unroll 1
    for (int lgi = 0; lgi < 2; ++lgi) {
        const int lg = oq * 2 + lgi;
        const int g  = half * NSLF + lg;
        const float* w2g = w2 + g * 49 * CRED;
        const float* b2g = b2 + g * 49;

        float acc[4][4];
        #pragma unroll
        for (int nt = 0; nt < 4; ++nt)
            #pragma unroll
            for (int c = 0; c < 4; ++c) acc[nt][c] = 0.f;

        #pragma clang loop unroll(disable)
        for (int mt = 0; mt < 3; ++mt) {
            half8 af;
            {
                const float* wr = w2g + (mt * 16 + r) * CRED + q * 8;
                float4 wa = *(const float4*)wr;
                float4 wb = *(const float4*)(wr + 4);
                af[0] = (_Float16)wa.x; af[1] = (_Float16)wa.y;
                af[2] = (_Float16)wa.z; af[3] = (_Float16)wa.w;
                af[4] = (_Float16)wb.x; af[5] = (_Float16)wb.y;
                af[6] = (_Float16)wb.z; af[7] = (_Float16)wb.w;
            }
            f32x4 d0 = __builtin_amdgcn_mfma_f32_16x16x32_f16(af, bfrag0, zero, 0, 0, 0);
            f32x4 d1 = __builtin_amdgcn_mfma_f32_16x16x32_f16(af, bfrag1, zero, 0, 0, 0);
            f32x4 d2 = __builtin_amdgcn_mfma_f32_16x16x32_f16(af, bfrag2, zero, 0, 0, 0);
            f32x4 d3 = __builtin_amdgcn_mfma_f32_16x16x32_f16(af, bfrag3, zero, 0, 0, 0);

            #pragma unroll
            for (int reg = 0; reg < 4; ++reg) {
                const int tap = mt * 16 + q * 4 + reg;
                const float bv = b2g[tap];
                const int di = (tap * 9363) >> 16;
                const int tapoff = tap + 7 * di;
                {
                    float wv = d0[reg] + bv;
                    int tp2 = pb0 + tapoff;
                    const float4 y4 = *(const float4*)&ytile[tp2 * NCHF + (((lg + tp2) & 7) << 2)];
                    acc[0][0] += wv * y4.x; acc[0][1] += wv * y4.y;
                    acc[0][2] += wv * y4.z; acc[0][3] += wv * y4.w;
                }
                {
                    float wv = d1[reg] + bv;
                    int tp2 = pb1 + tapoff;
                    const float4 y4 = *(const float4*)&ytile[tp2 * NCHF + (((lg + tp2) & 7) << 2)];
                    acc[1][0] += wv * y4.x; acc[1][1] += wv * y4.y;
                    acc[1][2] += wv * y4.z; acc[1][3] += wv * y4.w;
                }
                {
                    float wv = d2[reg] + bv;
                    int tp2 = pb2 + tapoff;
                    const float4 y4 = *(const float4*)&ytile[tp2 * NCHF + (((lg + tp2) & 7) << 2)];
                    acc[2][0] += wv * y4.x; acc[2][1] += wv * y4.y;
                    acc[2][2] += wv * y4.z; acc[2][3] += wv * y4.w;
                }
                {
                    float wv = d3[reg] + bv;
                    int tp2 = pb3 + tapoff;
                    const float4 y4 = *(const float4*)&ytile[tp2 * NCHF + (((lg + tp2) & 7) << 2)];
                    acc[3][0] += wv * y4.x; acc[3][1] += wv * y4.y;
                    acc[3][2] += wv * y4.z; acc[3][3] += wv * y4.w;
                }
            }
        }

        {
            half8 af;
            #pragma unroll
            for (int j = 0; j < 8; ++j) af[j] = (_Float16)0.f;
            if (r == 0) {
                const float* wr = w2g + 48 * CRED + q * 8;
                float4 wa = *(const float4*)wr;
                float4 wb = *(const float4*)(wr + 4);
                af[0] = (_Float16)wa.x; af[1] = (_Float16)wa.y;
                af[2] = (_Float16)wa.z; af[3] = (_Float16)wa.w;
                af[4] = (_Float16)wb.x; af[5] = (_Float16)wb.y;
                af[6] = (_Float16)wb.z; af[7] = (_Float16)wb.w;
            }
            f32x4 d0 = __builtin_amdgcn_mfma_f32_16x16x32_f16(af, bfrag0, zero, 0, 0, 0);
            f32x4 d1 = __builtin_amdgcn_mfma_f32_16x16x32_f16(af, bfrag1, zero, 0, 0, 0);
            f32x4 d2 = __builtin_amdgcn_mfma_f32_16x16x32_f16(af, bfrag2, zero, 0, 0, 0);
            f32x4 d3 = __builtin_amdgcn_mfma_f32_16x16x32_f16(af, bfrag3, zero, 0, 0, 0);

            const float bv = b2g[48];
            const int tapoff = 48 + 7 * 6;
            const bool live = (q == 0);
            {
                float wv = live ? (d0[0] + bv) : 0.f;
                int tp2 = pb0 + tapoff;
                const float4 y4 = *(const float4*)&ytile[tp2 * NCHF + (((lg + tp2) & 7) << 2)];
                acc[0][0] += wv * y4.x; acc[0][1] += wv * y4.y;
                acc[0][2] += wv * y4.z; acc[0][3] += wv * y4.w;
            }
            {
                float wv = live ? (d1[0] + bv) : 0.f;
                int tp2 = pb1 + tapoff;
                const float4 y4 = *(const float4*)&ytile[tp2 * NCHF + (((lg + tp2) & 7) << 2)];
                acc[1][0] += wv * y4.x; acc[1][1] += wv * y4.y;
                acc[1][2] += wv * y4.z; acc[1][3] += wv * y4.w;
            }
            {
                float wv = live ? (d2[0] + bv) : 0.f;
                int tp2 = pb2 + tapoff;
                const float4 y4 = *(const float4*)&ytile[tp2 * NCHF + (((lg + tp2) & 7) << 2)];
                acc[2][0] += wv * y4.x; acc[2][1] += wv * y4.y;
                acc[2][2] += wv * y4.z; acc[2][3] += wv * y4.w;
            }
            {
                float wv = live ? (d3[0] + bv) : 0.f;
                int tp2 = pb3 + tapoff;
                const float4 y4 = *(const float4*)&ytile[tp2 * NCHF + (((lg + tp2) & 7) << 2)];
                acc[3][0] += wv * y4.x; acc[3][1] += wv * y4.y;
                acc[3][2] += wv * y4.z; acc[3][3] += wv * y4.w;
            }
        }

        #pragma unroll
        for (int nt = 0; nt < 4; ++nt)
            #pragma unroll
            for (int c = 0; c < 4; ++c) {
                float v = acc[nt][c];
                v += __shfl_xor(v, 16);
                v += __shfl_xor(v, 32);
                acc[nt][c] = v;
            }

        size_t ob = ((size_t)(b * C64 + g * GC4) << 14) + pix;
        #pragma unroll
        for (int c = 0; c < 4; ++c) {
            float s0 = (q & 1) ? acc[1][c] : acc[0][c];
            float s1 = (q & 1) ? acc[3][c] : acc[2][c];
            float vv = (q & 2) ? s1 : s0;
            out[ob + ((size_t)c << 14)] = vv;
        }
    }
}

extern "C" void kernel_launch(void* const* d_in, const int* in_sizes, int n_in,
                              void* d_out, int out_size, void* d_ws, size_t ws_size,
                              hipStream_t stream) {
    const float* x   = (const float*)d_in[0];
    const float* y   = (const float*)d_in[1];
    const float* w1  = (const float*)d_in[2];
    const float* b1  = (const float*)d_in[3];
    const float* gma = (const float*)d_in[4];
    const float* bta = (const float*)d_in[5];
    const float* mu  = (const float*)d_in[6];
    const float* var = (const float*)d_in[7];
    const float* w2  = (const float*)d_in[8];
    const float* b2  = (const float*)d_in[9];
    float* out = (float*)d_out;

    const size_t t_bytes = (size_t)4 * 16384 * 32 * sizeof(_Float16);  // 4 MB
    if (ws_size >= t_bytes) {
        _Float16* t = (_Float16*)d_ws;
        hipLaunchKernelGGL(conv1_bn_relu, dim3(1024), dim3(256), 0, stream,
                           x, w1, b1, gma, bta, mu, var, t);
        hipLaunchKernelGGL(invol_agg, dim3(16, 16, 8), dim3(256), 0, stream,
                           y, t, w2, b2, out);
    } else {
        hipLaunchKernelGGL(involution_fused_fb, dim3(16, 16, 8), dim3(256), 0, stream,
                           x, y, w1, b1, gma, bta, mu, var, w2, b2, out);
    }
}

// Round 15
// 45.439 us; speedup vs baseline: 1.0646x; 1.0646x over previous
//
#include <hip/hip_runtime.h>

#define K7   7
#define PAD3 3
#define C64  64
#define CRED 32          // C/2
#define GC4  4
#define EPSV 1e-5f

typedef _Float16 half8 __attribute__((ext_vector_type(8)));
typedef _Float16 half4 __attribute__((ext_vector_type(4)));
typedef float    f32x4 __attribute__((ext_vector_type(4)));

// ============================= two-kernel path =============================
// ---- kernel 1: conv1 (1x1) + BN(eval) + ReLU -> t[b][pix][32] as f16 ----
__global__ __launch_bounds__(256, 4)
void conv1_bn_relu(const float* __restrict__ x,  const float* __restrict__ w1,
                   const float* __restrict__ b1, const float* __restrict__ gma,
                   const float* __restrict__ bta, const float* __restrict__ mu,
                   const float* __restrict__ var, _Float16* __restrict__ t)
{
    const int tid = threadIdx.x;
    const int p   = tid & 63;
    const int oq  = __builtin_amdgcn_readfirstlane(tid >> 6);
    const int task = blockIdx.x * 64 + p;           // 0 .. 65535
    const int b   = task >> 14;
    const int pix = task & 16383;

    float dot[8] = {0,0,0,0,0,0,0,0};
    const float* w1q = w1 + oq * 8 * C64;
    const float* xp  = x + ((size_t)b << 20) + pix;
    #pragma unroll 8
    for (int c = 0; c < C64; ++c) {
        float xc = xp[(size_t)c << 14];
        #pragma unroll
        for (int j = 0; j < 8; ++j) dot[j] += w1q[j * C64 + c] * xc;
    }
    _Float16 tv[8];
    #pragma unroll
    for (int j = 0; j < 8; ++j) {
        int o = oq * 8 + j;
        float sv = gma[o] * rsqrtf(var[o] + EPSV);
        float bb = (b1[o] - mu[o]) * sv + bta[o];
        tv[j] = (_Float16)fmaxf(dot[j] * sv + bb, 0.f);
    }
    *(half8*)&t[((size_t)((b << 14) + pix)) * 32 + oq * 8] = *(const half8*)tv;
}

// ---- kernel 2: per-pixel dynamic kernels (MFMA) + depthwise aggregation ----
// 8x16 pixel tile (128 px), quarter channels (16 ch, 4 groups, 1 group/wave).
#define TH   8
#define TW   16
#define HH2  14                     // TH + 6
#define HW2  22                     // TW + 6
#define NPIX2 (HH2 * HW2)           // 308
#define NSL2 4
#define YPS  20                     // f16 per pixel (40B): bank step 10, clean
#define W2ST 40
#define W2G  (49 * W2ST)

__global__ __launch_bounds__(256, 2)
void invol_agg(const float* __restrict__ y, const _Float16* __restrict__ t,
               const float* __restrict__ w2, const float* __restrict__ b2,
               float* __restrict__ out)
{
    __shared__ __align__(16) _Float16 ytile[NPIX2 * YPS];  // 12320 B
    __shared__ __align__(16) _Float16 w2h[NSL2 * W2G];     // 15680 B

    const int tid = threadIdx.x;
    // XCD-aware swizzle: 2048 blocks -> 8 chunks of 256 contiguous tiles
    const int wgid = blockIdx.x + (blockIdx.y << 3) + (blockIdx.z << 7);
    const int swz  = ((wgid & 7) << 8) | (wgid >> 3);
    const int bx = swz & 7, by = (swz >> 3) & 15, bz = swz >> 7;
    const int b = bz >> 2, quarter = bz & 3;
    const int gh0 = by * TH, gw0 = bx * TW;
    const int c0 = quarter * 16;

    const int p  = tid & 63;
    const int oq = __builtin_amdgcn_readfirstlane(tid >> 6);  // wave = group 0..3
    const int q  = p >> 4, r = p & 15;

    // --- issue B-fragment loads EARLY (8 row-tiles): hide under staging ---
    const _Float16* tb = t + ((size_t)(b << 14)) * 32;
    half8 bf0 = *(const half8*)&tb[(size_t)(((gh0 + 0) << 7) + gw0 + r) * 32 + q * 8];
    half8 bf1 = *(const half8*)&tb[(size_t)(((gh0 + 1) << 7) + gw0 + r) * 32 + q * 8];
    half8 bf2 = *(const half8*)&tb[(size_t)(((gh0 + 2) << 7) + gw0 + r) * 32 + q * 8];
    half8 bf3 = *(const half8*)&tb[(size_t)(((gh0 + 3) << 7) + gw0 + r) * 32 + q * 8];
    half8 bf4 = *(const half8*)&tb[(size_t)(((gh0 + 4) << 7) + gw0 + r) * 32 + q * 8];
    half8 bf5 = *(const half8*)&tb[(size_t)(((gh0 + 5) << 7) + gw0 + r) * 32 + q * 8];
    half8 bf6 = *(const half8*)&tb[(size_t)(((gh0 + 6) << 7) + gw0 + r) * 32 + q * 8];
    half8 bf7 = *(const half8*)&tb[(size_t)(((gh0 + 7) << 7) + gw0 + r) * 32 + q * 8];

    // --- stage y halo as f16: 16 channels, 4 cg groups x 308 pixels ---
    for (int u = tid; u < 4 * NPIX2; u += 256) {
        int cg   = u / NPIX2;
        int pixl = u - cg * NPIX2;
        int rr   = pixl / HW2;
        int col  = pixl - rr * HW2;
        int grow = gh0 - PAD3 + rr;
        int gcol = gw0 - PAD3 + col;
        half4 v = {(_Float16)0.f, (_Float16)0.f, (_Float16)0.f, (_Float16)0.f};
        if ((unsigned)grow < 128u && (unsigned)gcol < 128u) {
            const float* yp = y + ((size_t)(b * C64 + c0 + cg * 4) << 14) + (grow << 7) + gcol;
            v[0] = (_Float16)yp[0];
            v[1] = (_Float16)yp[1 << 14];
            v[2] = (_Float16)yp[2 << 14];
            v[3] = (_Float16)yp[3 << 14];
        }
        *(half4*)&ytile[pixl * YPS + cg * 4] = v;
    }

    // --- stage w2 (this block's 4 groups) as f16 [lg][49 x stride 40] ---
    for (int u = tid; u < NSL2 * 49 * 8; u += 256) {     // 1568 half4-units
        int lg  = u / 392;
        int rem = u - lg * 392;
        int row = rem >> 3;
        int k4  = (rem & 7) << 2;
        const float4 w4 = *(const float4*)&w2[(((quarter * NSL2 + lg) * 49 + row) << 5) + k4];
        half4 h;
        h[0] = (_Float16)w4.x; h[1] = (_Float16)w4.y;
        h[2] = (_Float16)w4.z; h[3] = (_Float16)w4.w;
        *(half4*)&w2h[lg * W2G + row * W2ST + k4] = h;
    }
    __syncthreads();

    // pixel-tile bases: nt = local row 0..7, lane col = r
    const int pbF0 = (0 * HW2 + r) * YPS + oq * 4;
    const int pbF1 = (1 * HW2 + r) * YPS + oq * 4;
    const int pbF2 = (2 * HW2 + r) * YPS + oq * 4;
    const int pbF3 = (3 * HW2 + r) * YPS + oq * 4;
    const int pbF4 = (4 * HW2 + r) * YPS + oq * 4;
    const int pbF5 = (5 * HW2 + r) * YPS + oq * 4;
    const int pbF6 = (6 * HW2 + r) * YPS + oq * 4;
    const int pbF7 = (7 * HW2 + r) * YPS + oq * 4;

    const f32x4 zero = {0.f, 0.f, 0.f, 0.f};

    const int g = quarter * NSL2 + oq;         // global group 0..15
    const float* b2g = b2 + g * 49;
    const _Float16* w2hg = w2h + oq * W2G;     // wave-uniform base

    float acc[8][4];
    #pragma unroll
    for (int nt = 0; nt < 8; ++nt)
        #pragma unroll
        for (int c = 0; c < 4; ++c) acc[nt][c] = 0.f;

#define AGG(NT, DV) do { \
        const half4 y4 = *(const half4*)&ytile[pbF##NT + toffF]; \
        const float wv = (DV)[reg]; \
        acc[NT][0] += (float)y4[0] * wv; acc[NT][1] += (float)y4[1] * wv; \
        acc[NT][2] += (float)y4[2] * wv; acc[NT][3] += (float)y4[3] * wv; \
    } while (0)

#define AGGT(NT, DV) do { \
        const half4 y4 = *(const half4*)&ytile[pbF##NT + toffF]; \
        const float wv = live ? ((DV)[0] + bv) : 0.f; \
        acc[NT][0] += (float)y4[0] * wv; acc[NT][1] += (float)y4[1] * wv; \
        acc[NT][2] += (float)y4[2] * wv; acc[NT][3] += (float)y4[3] * wv; \
    } while (0)

    // mt = 0..2 : rolled (liveness cap); A-frag from LDS, bias as C-init
    #pragma clang loop unroll(disable)
    for (int mt = 0; mt < 3; ++mt) {
        const half8 af = *(const half8*)&w2hg[(mt * 16 + r) * W2ST + q * 8];
        const int bi = mt * 16 + q * 4;
        const f32x4 cb = { b2g[bi+0], b2g[bi+1], b2g[bi+2], b2g[bi+3] };

        f32x4 d0 = __builtin_amdgcn_mfma_f32_16x16x32_f16(af, bf0, cb, 0, 0, 0);
        f32x4 d1 = __builtin_amdgcn_mfma_f32_16x16x32_f16(af, bf1, cb, 0, 0, 0);
        f32x4 d2 = __builtin_amdgcn_mfma_f32_16x16x32_f16(af, bf2, cb, 0, 0, 0);
        f32x4 d3 = __builtin_amdgcn_mfma_f32_16x16x32_f16(af, bf3, cb, 0, 0, 0);
        f32x4 d4 = __builtin_amdgcn_mfma_f32_16x16x32_f16(af, bf4, cb, 0, 0, 0);
        f32x4 d5 = __builtin_amdgcn_mfma_f32_16x16x32_f16(af, bf5, cb, 0, 0, 0);
        f32x4 d6 = __builtin_amdgcn_mfma_f32_16x16x32_f16(af, bf6, cb, 0, 0, 0);
        f32x4 d7 = __builtin_amdgcn_mfma_f32_16x16x32_f16(af, bf7, cb, 0, 0, 0);

        #pragma unroll
        for (int reg = 0; reg < 4; ++reg) {          // MUST stay fully unrolled
            const int tap = mt * 16 + q * 4 + reg;   // lane's tap, < 49
            const int di = (tap * 9363) >> 16;       // tap / 7
            const int toffF = (tap + 15 * di) * YPS; // (di*22 + dj) * YPS
            AGG(0, d0); AGG(1, d1); AGG(2, d2); AGG(3, d3);
            AGG(4, d4); AGG(5, d5); AGG(6, d6); AGG(7, d7);
        }
    }

    // mt = 3 : only tap 48 real (lane r==0 holds row 48; q==0 output)
    {
        half8 af = *(const half8*)&w2hg[48 * W2ST + q * 8];
        if (r != 0) {
            #pragma unroll
            for (int j = 0; j < 8; ++j) af[j] = (_Float16)0.f;
        }
        f32x4 d0 = __builtin_amdgcn_mfma_f32_16x16x32_f16(af, bf0, zero, 0, 0, 0);
        f32x4 d1 = __builtin_amdgcn_mfma_f32_16x16x32_f16(af, bf1, zero, 0, 0, 0);
        f32x4 d2 = __builtin_amdgcn_mfma_f32_16x16x32_f16(af, bf2, zero, 0, 0, 0);
        f32x4 d3 = __builtin_amdgcn_mfma_f32_16x16x32_f16(af, bf3, zero, 0, 0, 0);
        f32x4 d4 = __builtin_amdgcn_mfma_f32_16x16x32_f16(af, bf4, zero, 0, 0, 0);
        f32x4 d5 = __builtin_amdgcn_mfma_f32_16x16x32_f16(af, bf5, zero, 0, 0, 0);
        f32x4 d6 = __builtin_amdgcn_mfma_f32_16x16x32_f16(af, bf6, zero, 0, 0, 0);
        f32x4 d7 = __builtin_amdgcn_mfma_f32_16x16x32_f16(af, bf7, zero, 0, 0, 0);

        const float bv = b2g[48];
        const int toffF = (48 + 15 * 6) * YPS;       // (6*22+6)*YPS, uniform
        const bool live = (q == 0);
        AGGT(0, d0); AGGT(1, d1); AGGT(2, d2); AGGT(3, d3);
        AGGT(4, d4); AGGT(5, d5); AGGT(6, d6); AGGT(7, d7);
    }
#undef AGG
#undef AGGT

    // reduce tap-quadrant partials
    #pragma unroll
    for (int nt = 0; nt < 8; ++nt)
        #pragma unroll
        for (int c = 0; c < 4; ++c) {
            float v = acc[nt][c];
            v += __shfl_xor(v, 16);
            v += __shfl_xor(v, 32);
            acc[nt][c] = v;
        }

    // lane p (=16q+r) stores pixels (row q, col r) and (row q+4, col r)
    const size_t obase = ((size_t)(b * C64 + g * GC4) << 14);
    const int pixA = ((gh0 + q) << 7) + gw0 + r;
    const int pixB = ((gh0 + 4 + q) << 7) + gw0 + r;
    #pragma unroll
    for (int c = 0; c < 4; ++c) {
        float s0 = (q & 1) ? acc[1][c] : acc[0][c];
        float s1 = (q & 1) ? acc[3][c] : acc[2][c];
        out[obase + ((size_t)c << 14) + pixA] = (q & 2) ? s1 : s0;
        float s2 = (q & 1) ? acc[5][c] : acc[4][c];
        float s3 = (q & 1) ? acc[7][c] : acc[6][c];
        out[obase + ((size_t)c << 14) + pixB] = (q & 2) ? s3 : s2;
    }
}

// ======================= fused fallback (round-6, 60.8µs) =======================
#define TILE 8
#define HALO 14
#define NPIX (HALO * HALO)
#define NCHF 32
#define NSLF 8
#define TSTH 40

__global__ __launch_bounds__(256, 2)
void involution_fused_fb(const float* __restrict__ x, const float* __restrict__ y,
                         const float* __restrict__ w1, const float* __restrict__ b1,
                         const float* __restrict__ gma, const float* __restrict__ bta,
                         const float* __restrict__ mu,  const float* __restrict__ var,
                         const float* __restrict__ w2,  const float* __restrict__ b2,
                         float* __restrict__ out)
{
    __shared__ __align__(16) float    ytile[NPIX * NCHF];
    __shared__ __align__(16) _Float16 t_lds[64 * TSTH];

    const int tid = threadIdx.x;
    const int bx = blockIdx.x, by = blockIdx.y, bz = blockIdx.z;
    const int b = bz >> 1, half = bz & 1;
    const int gh0 = by * TILE, gw0 = bx * TILE;
    const int c0 = half * NCHF;

    for (int li = tid; li < NCHF * NPIX; li += 256) {
        int c    = li / NPIX;
        int pixl = li - c * NPIX;
        int rr   = pixl / HALO;
        int col  = pixl - rr * HALO;
        int grow = gh0 - PAD3 + rr;
        int gcol = gw0 - PAD3 + col;
        float v = 0.f;
        if ((unsigned)grow < 128u && (unsigned)gcol < 128u)
            v = y[((size_t)(b * C64 + c0 + c) << 14) + (grow << 7) + gcol];
        int slot = ((c >> 2) + pixl) & 7;
        ytile[pixl * NCHF + slot * 4 + (c & 3)] = v;
    }

    const int p  = tid & 63;
    const int ph = p >> 3, pw = p & 7;
    const int oq = __builtin_amdgcn_readfirstlane(tid >> 6);
    const int pix = ((gh0 + ph) << 7) + (gw0 + pw);
    {
        float dot[8] = {0,0,0,0,0,0,0,0};
        const float* w1q = w1 + oq * 8 * C64;
        const float* xp  = x + ((size_t)(b * C64) << 14) + pix;
        #pragma unroll 8
        for (int c = 0; c < C64; ++c) {
            float xc = xp[(size_t)c << 14];
            #pragma unroll
            for (int j = 0; j < 8; ++j) dot[j] += w1q[j * C64 + c] * xc;
        }
        _Float16 tv16[8];
        #pragma unroll
        for (int j = 0; j < 8; ++j) {
            int o = oq * 8 + j;
            float sv = gma[o] * rsqrtf(var[o] + EPSV);
            float bb = (b1[o] - mu[o]) * sv + bta[o];
            tv16[j] = (_Float16)fmaxf(dot[j] * sv + bb, 0.f);
        }
        *(half8*)&t_lds[p * TSTH + oq * 8] = *(const half8*)tv16;
    }
    __syncthreads();

    const int q = p >> 4;
    const int r = p & 15;

    half8 bfrag0 = *(const half8*)&t_lds[( 0 + r) * TSTH + q * 8];
    half8 bfrag1 = *(const half8*)&t_lds[(16 + r) * TSTH + q * 8];
    half8 bfrag2 = *(const half8*)&t_lds[(32 + r) * TSTH + q * 8];
    half8 bfrag3 = *(const half8*)&t_lds[(48 + r) * TSTH + q * 8];

    const int pb0 = (0 + (r >> 3)) * HALO + (r & 7);
    const int pb1 = (2 + (r >> 3)) * HALO + (r & 7);
    const int pb2 = (4 + (r >> 3)) * HALO + (r & 7);
    const int pb3 = (6 + (r >> 3)) * HALO + (r & 7);

    const f32x4 zero = {0.f, 0.f, 0.f, 0.f};

    #pragma unroll 1
    for (int lgi = 0; lgi < 2; ++lgi) {
        const int lg = oq * 2 + lgi;
        const int g  = half * NSLF + lg;
        const float* w2g = w2 + g * 49 * CRED;
        const float* b2g = b2 + g * 49;

        float acc[4][4];
        #pragma unroll
        for (int nt = 0; nt < 4; ++nt)
            #pragma unroll
            for (int c = 0; c < 4; ++c) acc[nt][c] = 0.f;

        #pragma clang loop unroll(disable)
        for (int mt = 0; mt < 3; ++mt) {
            half8 af;
            {
                const float* wr = w2g + (mt * 16 + r) * CRED + q * 8;
                float4 wa = *(const float4*)wr;
                float4 wb = *(const float4*)(wr + 4);
                af[0] = (_Float16)wa.x; af[1] = (_Float16)wa.y;
                af[2] = (_Float16)wa.z; af[3] = (_Float16)wa.w;
                af[4] = (_Float16)wb.x; af[5] = (_Float16)wb.y;
                af[6] = (_Float16)wb.z; af[7] = (_Float16)wb.w;
            }
            f32x4 d0 = __builtin_amdgcn_mfma_f32_16x16x32_f16(af, bfrag0, zero, 0, 0, 0);
            f32x4 d1 = __builtin_amdgcn_mfma_f32_16x16x32_f16(af, bfrag1, zero, 0, 0, 0);
            f32x4 d2 = __builtin_amdgcn_mfma_f32_16x16x32_f16(af, bfrag2, zero, 0, 0, 0);
            f32x4 d3 = __builtin_amdgcn_mfma_f32_16x16x32_f16(af, bfrag3, zero, 0, 0, 0);

            #pragma unroll
            for (int reg = 0; reg < 4; ++reg) {
                const int tap = mt * 16 + q * 4 + reg;
                const float bv = b2g[tap];
                const int di = (tap * 9363) >> 16;
                const int tapoff = tap + 7 * di;
                {
                    float wv = d0[reg] + bv;
                    int tp2 = pb0 + tapoff;
                    const float4 y4 = *(const float4*)&ytile[tp2 * NCHF + (((lg + tp2) & 7) << 2)];
                    acc[0][0] += wv * y4.x; acc[0][1] += wv * y4.y;
                    acc[0][2] += wv * y4.z; acc[0][3] += wv * y4.w;
                }
                {
                    float wv = d1[reg] + bv;
                    int tp2 = pb1 + tapoff;
                    const float4 y4 = *(const float4*)&ytile[tp2 * NCHF + (((lg + tp2) & 7) << 2)];
                    acc[1][0] += wv * y4.x; acc[1][1] += wv * y4.y;
                    acc[1][2] += wv * y4.z; acc[1][3] += wv * y4.w;
                }
                {
                    float wv = d2[reg] + bv;
                    int tp2 = pb2 + tapoff;
                    const float4 y4 = *(const float4*)&ytile[tp2 * NCHF + (((lg + tp2) & 7) << 2)];
                    acc[2][0] += wv * y4.x; acc[2][1] += wv * y4.y;
                    acc[2][2] += wv * y4.z; acc[2][3] += wv * y4.w;
                }
                {
                    float wv = d3[reg] + bv;
                    int tp2 = pb3 + tapoff;
                    const float4 y4 = *(const float4*)&ytile[tp2 * NCHF + (((lg + tp2) & 7) << 2)];
                    acc[3][0] += wv * y4.x; acc[3][1] += wv * y4.y;
                    acc[3][2] += wv * y4.z; acc[3][3] += wv * y4.w;
                }
            }
        }

        {
            half8 af;
            #pragma unroll
            for (int j = 0; j < 8; ++j) af[j] = (_Float16)0.f;
            if (r == 0) {
                const float* wr = w2g + 48 * CRED + q * 8;
                float4 wa = *(const float4*)wr;
                float4 wb = *(const float4*)(wr + 4);
                af[0] = (_Float16)wa.x; af[1] = (_Float16)wa.y;
                af[2] = (_Float16)wa.z; af[3] = (_Float16)wa.w;
                af[4] = (_Float16)wb.x; af[5] = (_Float16)wb.y;
                af[6] = (_Float16)wb.z; af[7] = (_Float16)wb.w;
            }
            f32x4 d0 = __builtin_amdgcn_mfma_f32_16x16x32_f16(af, bfrag0, zero, 0, 0, 0);
            f32x4 d1 = __builtin_amdgcn_mfma_f32_16x16x32_f16(af, bfrag1, zero, 0, 0, 0);
            f32x4 d2 = __builtin_amdgcn_mfma_f32_16x16x32_f16(af, bfrag2, zero, 0, 0, 0);
            f32x4 d3 = __builtin_amdgcn_mfma_f32_16x16x32_f16(af, bfrag3, zero, 0, 0, 0);

            const float bv = b2g[48];
            const int tapoff = 48 + 7 * 6;
            const bool live = (q == 0);
            {
                float wv = live ? (d0[0] + bv) : 0.f;
                int tp2 = pb0 + tapoff;
                const float4 y4 = *(const float4*)&ytile[tp2 * NCHF + (((lg + tp2) & 7) << 2)];
                acc[0][0] += wv * y4.x; acc[0][1] += wv * y4.y;
                acc[0][2] += wv * y4.z; acc[0][3] += wv * y4.w;
            }
            {
                float wv = live ? (d1[0] + bv) : 0.f;
                int tp2 = pb1 + tapoff;
                const float4 y4 = *(const float4*)&ytile[tp2 * NCHF + (((lg + tp2) & 7) << 2)];
                acc[1][0] += wv * y4.x; acc[1][1] += wv * y4.y;
                acc[1][2] += wv * y4.z; acc[1][3] += wv * y4.w;
            }
            {
                float wv = live ? (d2[0] + bv) : 0.f;
                int tp2 = pb2 + tapoff;
                const float4 y4 = *(const float4*)&ytile[tp2 * NCHF + (((lg + tp2) & 7) << 2)];
                acc[2][0] += wv * y4.x; acc[2][1] += wv * y4.y;
                acc[2][2] += wv * y4.z; acc[2][3] += wv * y4.w;
            }
            {
                float wv = live ? (d3[0] + bv) : 0.f;
                int tp2 = pb3 + tapoff;
                const float4 y4 = *(const float4*)&ytile[tp2 * NCHF + (((lg + tp2) & 7) << 2)];
                acc[3][0] += wv * y4.x; acc[3][1] += wv * y4.y;
                acc[3][2] += wv * y4.z; acc[3][3] += wv * y4.w;
            }
        }

        #pragma unroll
        for (int nt = 0; nt < 4; ++nt)
            #pragma unroll
            for (int c = 0; c < 4; ++c) {
                float v = acc[nt][c];
                v += __shfl_xor(v, 16);
                v += __shfl_xor(v, 32);
                acc[nt][c] = v;
            }

        size_t ob = ((size_t)(b * C64 + g * GC4) << 14) + pix;
        #pragma unroll
        for (int c = 0; c < 4; ++c) {
            float s0 = (q & 1) ? acc[1][c] : acc[0][c];
            float s1 = (q & 1) ? acc[3][c] : acc[2][c];
            float vv = (q & 2) ? s1 : s0;
            out[ob + ((size_t)c << 14)] = vv;
        }
    }
}

extern "C" void kernel_launch(void* const* d_in, const int* in_sizes, int n_in,
                              void* d_out, int out_size, void* d_ws, size_t ws_size,
                              hipStream_t stream) {
    const float* x   = (const float*)d_in[0];
    const float* y   = (const float*)d_in[1];
    const float* w1  = (const float*)d_in[2];
    const float* b1  = (const float*)d_in[3];
    const float* gma = (const float*)d_in[4];
    const float* bta = (const float*)d_in[5];
    const float* mu  = (const float*)d_in[6];
    const float* var = (const float*)d_in[7];
    const float* w2  = (const float*)d_in[8];
    const float* b2  = (const float*)d_in[9];
    float* out = (float*)d_out;

    const size_t t_bytes = (size_t)4 * 16384 * 32 * sizeof(_Float16);  // 4 MB
    if (ws_size >= t_bytes) {
        _Float16* t = (_Float16*)d_ws;
        hipLaunchKernelGGL(conv1_bn_relu, dim3(1024), dim3(256), 0, stream,
                           x, w1, b1, gma, bta, mu, var, t);
        hipLaunchKernelGGL(invol_agg, dim3(8, 16, 16), dim3(256), 0, stream,
                           y, t, w2, b2, out);
    } else {
        hipLaunchKernelGGL(involution_fused_fb, dim3(16, 16, 8), dim3(256), 0, stream,
                           x, y, w1, b1, gma, bta, mu, var, w2, b2, out);
    }
}

// Round 16
// 42.629 us; speedup vs baseline: 1.1347x; 1.0659x over previous
//
#include <hip/hip_runtime.h>

#define K7   7
#define PAD3 3
#define C64  64
#define CRED 32          // C/2
#define GC4  4
#define EPSV 1e-5f

#define TILE 8                      // 8x8 pixels per block (k2 / fused)
#define HALO 14                     // TILE + K7 - 1
#define NPIX (HALO * HALO)          // 196

typedef _Float16 half8 __attribute__((ext_vector_type(8)));
typedef _Float16 half4 __attribute__((ext_vector_type(4)));
typedef float    f32x4 __attribute__((ext_vector_type(4)));

// ============================= two-kernel path =============================
// ---- kernel 1: conv1 (1x1) + BN(eval) + ReLU -> t[b][pix][32] as f16 ----
__global__ __launch_bounds__(256, 4)
void conv1_bn_relu(const float* __restrict__ x,  const float* __restrict__ w1,
                   const float* __restrict__ b1, const float* __restrict__ gma,
                   const float* __restrict__ bta, const float* __restrict__ mu,
                   const float* __restrict__ var, _Float16* __restrict__ t)
{
    const int tid = threadIdx.x;
    const int p   = tid & 63;
    const int oq  = __builtin_amdgcn_readfirstlane(tid >> 6);
    const int task = blockIdx.x * 64 + p;           // 0 .. 65535
    const int b   = task >> 14;
    const int pix = task & 16383;

    float dot[8] = {0,0,0,0,0,0,0,0};
    const float* w1q = w1 + oq * 8 * C64;
    const float* xp  = x + ((size_t)b << 20) + pix;
    #pragma unroll 8
    for (int c = 0; c < C64; ++c) {
        float xc = xp[(size_t)c << 14];
        #pragma unroll
        for (int j = 0; j < 8; ++j) dot[j] += w1q[j * C64 + c] * xc;
    }
    _Float16 tv[8];
    #pragma unroll
    for (int j = 0; j < 8; ++j) {
        int o = oq * 8 + j;
        float sv = gma[o] * rsqrtf(var[o] + EPSV);
        float bb = (b1[o] - mu[o]) * sv + bta[o];
        tv[j] = (_Float16)fmaxf(dot[j] * sv + bb, 0.f);
    }
    *(half8*)&t[((size_t)((b << 14) + pix)) * 32 + oq * 8] = *(const half8*)tv;
}

// ---- kernel 2: per-pixel dynamic kernels (MFMA) + depthwise aggregation ----
// Quarter-channel blocks, 1 group/wave, PER-WAVE staging, NO block barrier:
// each wave's ytile slice / w2 group / bias are private to that wave.
#define NCH2 16                     // y-channels per block (quarter of 64)
#define NSL2 4                      // channel-groups per block (1 per wave)
#define YPS  20                     // ytile per-pixel stride in f16 (40B)
#define W2ST 40                     // w2h row stride in f16 (80B, 16B-aligned)
#define W2G  (49 * W2ST)            // 1960 f16 per group

__global__ __launch_bounds__(256, 4)
void invol_agg(const float* __restrict__ y, const _Float16* __restrict__ t,
               const float* __restrict__ w2, const float* __restrict__ b2,
               float* __restrict__ out)
{
    __shared__ __align__(16) _Float16 ytile[NPIX * YPS];   //  7840 B
    __shared__ __align__(16) _Float16 w2h[NSL2 * W2G];     // 15680 B

    const int tid = threadIdx.x;
    // XCD-aware swizzle: 4096 blocks -> 8 chunks of 512 contiguous tiles
    const int wgid = blockIdx.x + (blockIdx.y << 4) + (blockIdx.z << 8);
    const int swz  = ((wgid & 7) << 9) | (wgid >> 3);
    const int bx = swz & 15, by = (swz >> 4) & 15, bz = swz >> 8;
    const int b = bz >> 2, quarter = bz & 3;
    const int gh0 = by * TILE, gw0 = bx * TILE;
    const int c0 = quarter * NCH2;

    const int p  = tid & 63;
    const int ph = p >> 3, pw = p & 7;
    const int oq = __builtin_amdgcn_readfirstlane(tid >> 6);  // wave = group 0..3
    const int q  = p >> 4, r = p & 15;
    const int pix = ((gh0 + ph) << 7) + (gw0 + pw);

    const int g = quarter * NSL2 + oq;         // global group 0..15

    // --- issue B-fragment loads EARLY: latency hides under staging ---
    const _Float16* tb = t + ((size_t)(b << 14)) * 32;
    const int rr8 = r >> 3, rc = r & 7;
    half8 bfrag0 = *(const half8*)&tb[(size_t)(((gh0 + 0 + rr8) << 7) + gw0 + rc) * 32 + q * 8];
    half8 bfrag1 = *(const half8*)&tb[(size_t)(((gh0 + 2 + rr8) << 7) + gw0 + rc) * 32 + q * 8];
    half8 bfrag2 = *(const half8*)&tb[(size_t)(((gh0 + 4 + rr8) << 7) + gw0 + rc) * 32 + q * 8];
    half8 bfrag3 = *(const half8*)&tb[(size_t)(((gh0 + 6 + rr8) << 7) + gw0 + rc) * 32 + q * 8];

    // --- per-wave y halo staging: wave oq stages ONLY its 4 channels ---
    #pragma unroll
    for (int i = 0; i < 4; ++i) {
        int pixl = p + i * 64;                 // 0..195
        if (pixl < NPIX) {
            int rr   = pixl / HALO;
            int col  = pixl - rr * HALO;
            int grow = gh0 - PAD3 + rr;
            int gcol = gw0 - PAD3 + col;
            half4 v = {(_Float16)0.f, (_Float16)0.f, (_Float16)0.f, (_Float16)0.f};
            if ((unsigned)grow < 128u && (unsigned)gcol < 128u) {
                const float* yp = y + ((size_t)(b * C64 + c0 + oq * 4) << 14) + (grow << 7) + gcol;
                v[0] = (_Float16)yp[0];
                v[1] = (_Float16)yp[1 << 14];
                v[2] = (_Float16)yp[2 << 14];
                v[3] = (_Float16)yp[3 << 14];
            }
            *(half4*)&ytile[pixl * YPS + oq * 4] = v;
        }
    }

    // --- per-wave w2 staging: wave oq stages ONLY its group ---
    #pragma unroll
    for (int i = 0; i < 7; ++i) {
        int u = p + i * 64;                    // 0..391 (49 rows x 8 half4-units)
        if (u < 392) {
            int row = u >> 3;
            int k4  = (u & 7) << 2;
            const float4 w4 = *(const float4*)&w2[((g * 49 + row) << 5) + k4];
            half4 h;
            h[0] = (_Float16)w4.x; h[1] = (_Float16)w4.y;
            h[2] = (_Float16)w4.z; h[3] = (_Float16)w4.w;
            *(half4*)&w2h[oq * W2G + row * W2ST + k4] = h;
        }
    }
    // NO __syncthreads(): each wave reads only what it wrote; the compiler's
    // lgkmcnt wait before the first dependent ds_read is the only sync needed.

    // per-lane f16-index bases into ytile: tp2*YPS + oq*4
    const int pbF0 = ((0 + rr8) * HALO + rc) * YPS + oq * 4;
    const int pbF1 = ((2 + rr8) * HALO + rc) * YPS + oq * 4;
    const int pbF2 = ((4 + rr8) * HALO + rc) * YPS + oq * 4;
    const int pbF3 = ((6 + rr8) * HALO + rc) * YPS + oq * 4;

    const f32x4 zero = {0.f, 0.f, 0.f, 0.f};

    const float* b2g = b2 + g * 49;
    const _Float16* w2hg = w2h + oq * W2G;     // wave-uniform base

    float acc[4][4];
    #pragma unroll
    for (int nt = 0; nt < 4; ++nt)
        #pragma unroll
        for (int c = 0; c < 4; ++c) acc[nt][c] = 0.f;

    // mt = 0..2 : rolled (liveness cap); A-frag from LDS, bias as C-init
    #pragma clang loop unroll(disable)
    for (int mt = 0; mt < 3; ++mt) {
        const half8 af = *(const half8*)&w2hg[(mt * 16 + r) * W2ST + q * 8];
        const int bi = mt * 16 + q * 4;
        const f32x4 cb = { b2g[bi+0], b2g[bi+1], b2g[bi+2], b2g[bi+3] };

        f32x4 d0 = __builtin_amdgcn_mfma_f32_16x16x32_f16(af, bfrag0, cb, 0, 0, 0);
        f32x4 d1 = __builtin_amdgcn_mfma_f32_16x16x32_f16(af, bfrag1, cb, 0, 0, 0);
        f32x4 d2 = __builtin_amdgcn_mfma_f32_16x16x32_f16(af, bfrag2, cb, 0, 0, 0);
        f32x4 d3 = __builtin_amdgcn_mfma_f32_16x16x32_f16(af, bfrag3, cb, 0, 0, 0);

        #pragma unroll
        for (int reg = 0; reg < 4; ++reg) {          // MUST stay fully unrolled
            const int tap = mt * 16 + q * 4 + reg;   // lane's tap, < 49
            const int di = (tap * 9363) >> 16;       // tap / 7
            const int toffF = (tap + 7 * di) * YPS;  // (di*14 + dj) * YPS
            {
                const float wv = d0[reg];
                const half4 y4 = *(const half4*)&ytile[pbF0 + toffF];
                acc[0][0] += (float)y4[0] * wv; acc[0][1] += (float)y4[1] * wv;
                acc[0][2] += (float)y4[2] * wv; acc[0][3] += (float)y4[3] * wv;
            }
            {
                const float wv = d1[reg];
                const half4 y4 = *(const half4*)&ytile[pbF1 + toffF];
                acc[1][0] += (float)y4[0] * wv; acc[1][1] += (float)y4[1] * wv;
                acc[1][2] += (float)y4[2] * wv; acc[1][3] += (float)y4[3] * wv;
            }
            {
                const float wv = d2[reg];
                const half4 y4 = *(const half4*)&ytile[pbF2 + toffF];
                acc[2][0] += (float)y4[0] * wv; acc[2][1] += (float)y4[1] * wv;
                acc[2][2] += (float)y4[2] * wv; acc[2][3] += (float)y4[3] * wv;
            }
            {
                const float wv = d3[reg];
                const half4 y4 = *(const half4*)&ytile[pbF3 + toffF];
                acc[3][0] += (float)y4[0] * wv; acc[3][1] += (float)y4[1] * wv;
                acc[3][2] += (float)y4[2] * wv; acc[3][3] += (float)y4[3] * wv;
            }
        }
    }

    // mt = 3 : only tap 48 real (lane r==0 holds row 48; q==0 output)
    {
        half8 af = *(const half8*)&w2hg[48 * W2ST + q * 8];
        if (r != 0) {
            #pragma unroll
            for (int j = 0; j < 8; ++j) af[j] = (_Float16)0.f;
        }
        f32x4 d0 = __builtin_amdgcn_mfma_f32_16x16x32_f16(af, bfrag0, zero, 0, 0, 0);
        f32x4 d1 = __builtin_amdgcn_mfma_f32_16x16x32_f16(af, bfrag1, zero, 0, 0, 0);
        f32x4 d2 = __builtin_amdgcn_mfma_f32_16x16x32_f16(af, bfrag2, zero, 0, 0, 0);
        f32x4 d3 = __builtin_amdgcn_mfma_f32_16x16x32_f16(af, bfrag3, zero, 0, 0, 0);

        const float bv = b2g[48];
        const int toffF = (48 + 7 * 6) * YPS;        // 90*YPS, uniform
        const bool live = (q == 0);
        {
            float wv = live ? (d0[0] + bv) : 0.f;
            const half4 y4 = *(const half4*)&ytile[pbF0 + toffF];
            acc[0][0] += (float)y4[0] * wv; acc[0][1] += (float)y4[1] * wv;
            acc[0][2] += (float)y4[2] * wv; acc[0][3] += (float)y4[3] * wv;
        }
        {
            float wv = live ? (d1[0] + bv) : 0.f;
            const half4 y4 = *(const half4*)&ytile[pbF1 + toffF];
            acc[1][0] += (float)y4[0] * wv; acc[1][1] += (float)y4[1] * wv;
            acc[1][2] += (float)y4[2] * wv; acc[1][3] += (float)y4[3] * wv;
        }
        {
            float wv = live ? (d2[0] + bv) : 0.f;
            const half4 y4 = *(const half4*)&ytile[pbF2 + toffF];
            acc[2][0] += (float)y4[0] * wv; acc[2][1] += (float)y4[1] * wv;
            acc[2][2] += (float)y4[2] * wv; acc[2][3] += (float)y4[3] * wv;
        }
        {
            float wv = live ? (d3[0] + bv) : 0.f;
            const half4 y4 = *(const half4*)&ytile[pbF3 + toffF];
            acc[3][0] += (float)y4[0] * wv; acc[3][1] += (float)y4[1] * wv;
            acc[3][2] += (float)y4[2] * wv; acc[3][3] += (float)y4[3] * wv;
        }
    }

    #pragma unroll
    for (int nt = 0; nt < 4; ++nt)
        #pragma unroll
        for (int c = 0; c < 4; ++c) {
            float v = acc[nt][c];
            v += __shfl_xor(v, 16);
            v += __shfl_xor(v, 32);
            acc[nt][c] = v;
        }

    size_t ob = ((size_t)(b * C64 + g * GC4) << 14) + pix;
    #pragma unroll
    for (int c = 0; c < 4; ++c) {
        float s0 = (q & 1) ? acc[1][c] : acc[0][c];
        float s1 = (q & 1) ? acc[3][c] : acc[2][c];
        float vv = (q & 2) ? s1 : s0;
        out[ob + ((size_t)c << 14)] = vv;
    }
}

// ======================= fused fallback (round-6, 60.8µs) =======================
#define NCHF 32
#define NSLF 8
#define TSTH 40

__global__ __launch_bounds__(256, 2)
void involution_fused_fb(const float* __restrict__ x, const float* __restrict__ y,
                         const float* __restrict__ w1, const float* __restrict__ b1,
                         const float* __restrict__ gma, const float* __restrict__ bta,
                         const float* __restrict__ mu,  const float* __restrict__ var,
                         const float* __restrict__ w2,  const float* __restrict__ b2,
                         float* __restrict__ out)
{
    __shared__ __align__(16) float    ytile[NPIX * NCHF];
    __shared__ __align__(16) _Float16 t_lds[64 * TSTH];

    const int tid = threadIdx.x;
    const int bx = blockIdx.x, by = blockIdx.y, bz = blockIdx.z;
    const int b = bz >> 1, half = bz & 1;
    const int gh0 = by * TILE, gw0 = bx * TILE;
    const int c0 = half * NCHF;

    for (int li = tid; li < NCHF * NPIX; li += 256) {
        int c    = li / NPIX;
        int pixl = li - c * NPIX;
        int rr   = pixl / HALO;
        int col  = pixl - rr * HALO;
        int grow = gh0 - PAD3 + rr;
        int gcol = gw0 - PAD3 + col;
        float v = 0.f;
        if ((unsigned)grow < 128u && (unsigned)gcol < 128u)
            v = y[((size_t)(b * C64 + c0 + c) << 14) + (grow << 7) + gcol];
        int slot = ((c >> 2) + pixl) & 7;
        ytile[pixl * NCHF + slot * 4 + (c & 3)] = v;
    }

    const int p  = tid & 63;
    const int ph = p >> 3, pw = p & 7;
    const int oq = __builtin_amdgcn_readfirstlane(tid >> 6);
    const int pix = ((gh0 + ph) << 7) + (gw0 + pw);
    {
        float dot[8] = {0,0,0,0,0,0,0,0};
        const float* w1q = w1 + oq * 8 * C64;
        const float* xp  = x + ((size_t)(b * C64) << 14) + pix;
        #pragma unroll 8
        for (int c = 0; c < C64; ++c) {
            float xc = xp[(size_t)c << 14];
            #pragma unroll
            for (int j = 0; j < 8; ++j) dot[j] += w1q[j * C64 + c] * xc;
        }
        _Float16 tv16[8];
        #pragma unroll
        for (int j = 0; j < 8; ++j) {
            int o = oq * 8 + j;
            float sv = gma[o] * rsqrtf(var[o] + EPSV);
            float bb = (b1[o] - mu[o]) * sv + bta[o];
            tv16[j] = (_Float16)fmaxf(dot[j] * sv + bb, 0.f);
        }
        *(half8*)&t_lds[p * TSTH + oq * 8] = *(const half8*)tv16;
    }
    __syncthreads();

    const int q = p >> 4;
    const int r = p & 15;

    half8 bfrag0 = *(const half8*)&t_lds[( 0 + r) * TSTH + q * 8];
    half8 bfrag1 = *(const half8*)&t_lds[(16 + r) * TSTH + q * 8];
    half8 bfrag2 = *(const half8*)&t_lds[(32 + r) * TSTH + q * 8];
    half8 bfrag3 = *(const half8*)&t_lds[(48 + r) * TSTH + q * 8];

    const int pb0 = (0 + (r >> 3)) * HALO + (r & 7);
    const int pb1 = (2 + (r >> 3)) * HALO + (r & 7);
    const int pb2 = (4 + (r >> 3)) * HALO + (r & 7);
    const int pb3 = (6 + (r >> 3)) * HALO + (r & 7);

    const f32x4 zero = {0.f, 0.f, 0.f, 0.f};

    #pragma unroll 1
    for (int lgi = 0; lgi < 2; ++lgi) {
        const int lg = oq * 2 + lgi;
        const int g  = half * NSLF + lg;
        const float* w2g = w2 + g * 49 * CRED;
        const float* b2g = b2 + g * 49;

        float acc[4][4];
        #pragma unroll
        for (int nt = 0; nt < 4; ++nt)
            #pragma unroll
            for (int c = 0; c < 4; ++c) acc[nt][c] = 0.f;

        #pragma clang loop unroll(disable)
        for (int mt = 0; mt < 3; ++mt) {
            half8 af;
            {
                const float* wr = w2g + (mt * 16 + r) * CRED + q * 8;
                float4 wa = *(const float4*)wr;
                float4 wb = *(const float4*)(wr + 4);
                af[0] = (_Float16)wa.x; af[1] = (_Float16)wa.y;
                af[2] = (_Float16)wa.z; af[3] = (_Float16)wa.w;
                af[4] = (_Float16)wb.x; af[5] = (_Float16)wb.y;
                af[6] = (_Float16)wb.z; af[7] = (_Float16)wb.w;
            }
            f32x4 d0 = __builtin_amdgcn_mfma_f32_16x16x32_f16(af, bfrag0, zero, 0, 0, 0);
            f32x4 d1 = __builtin_amdgcn_mfma_f32_16x16x32_f16(af, bfrag1, zero, 0, 0, 0);
            f32x4 d2 = __builtin_amdgcn_mfma_f32_16x16x32_f16(af, bfrag2, zero, 0, 0, 0);
            f32x4 d3 = __builtin_amdgcn_mfma_f32_16x16x32_f16(af, bfrag3, zero, 0, 0, 0);

            #pragma unroll
            for (int reg = 0; reg < 4; ++reg) {
                const int tap = mt * 16 + q * 4 + reg;
                const float bv = b2g[tap];
                const int di = (tap * 9363) >> 16;
                const int tapoff = tap + 7 * di;
                {
                    float wv = d0[reg] + bv;
                    int tp2 = pb0 + tapoff;
                    const float4 y4 = *(const float4*)&ytile[tp2 * NCHF + (((lg + tp2) & 7) << 2)];
                    acc[0][0] += wv * y4.x; acc[0][1] += wv * y4.y;
                    acc[0][2] += wv * y4.z; acc[0][3] += wv * y4.w;
                }
                {
                    float wv = d1[reg] + bv;
                    int tp2 = pb1 + tapoff;
                    const float4 y4 = *(const float4*)&ytile[tp2 * NCHF + (((lg + tp2) & 7) << 2)];
                    acc[1][0] += wv * y4.x; acc[1][1] += wv * y4.y;
                    acc[1][2] += wv * y4.z; acc[1][3] += wv * y4.w;
                }
                {
                    float wv = d2[reg] + bv;
                    int tp2 = pb2 + tapoff;
                    const float4 y4 = *(const float4*)&ytile[tp2 * NCHF + (((lg + tp2) & 7) << 2)];
                    acc[2][0] += wv * y4.x; acc[2][1] += wv * y4.y;
                    acc[2][2] += wv * y4.z; acc[2][3] += wv * y4.w;
                }
                {
                    float wv = d3[reg] + bv;
                    int tp2 = pb3 + tapoff;
                    const float4 y4 = *(const float4*)&ytile[tp2 * NCHF + (((lg + tp2) & 7) << 2)];
                    acc[3][0] += wv * y4.x; acc[3][1] += wv * y4.y;
                    acc[3][2] += wv * y4.z; acc[3][3] += wv * y4.w;
                }
            }
        }

        {
            half8 af;
            #pragma unroll
            for (int j = 0; j < 8; ++j) af[j] = (_Float16)0.f;
            if (r == 0) {
                const float* wr = w2g + 48 * CRED + q * 8;
                float4 wa = *(const float4*)wr;
                float4 wb = *(const float4*)(wr + 4);
                af[0] = (_Float16)wa.x; af[1] = (_Float16)wa.y;
                af[2] = (_Float16)wa.z; af[3] = (_Float16)wa.w;
                af[4] = (_Float16)wb.x; af[5] = (_Float16)wb.y;
                af[6] = (_Float16)wb.z; af[7] = (_Float16)wb.w;
            }
            f32x4 d0 = __builtin_amdgcn_mfma_f32_16x16x32_f16(af, bfrag0, zero, 0, 0, 0);
            f32x4 d1 = __builtin_amdgcn_mfma_f32_16x16x32_f16(af, bfrag1, zero, 0, 0, 0);
            f32x4 d2 = __builtin_amdgcn_mfma_f32_16x16x32_f16(af, bfrag2, zero, 0, 0, 0);
            f32x4 d3 = __builtin_amdgcn_mfma_f32_16x16x32_f16(af, bfrag3, zero, 0, 0, 0);

            const float bv = b2g[48];
            const int tapoff = 48 + 7 * 6;
            const bool live = (q == 0);
            {
                float wv = live ? (d0[0] + bv) : 0.f;
                int tp2 = pb0 + tapoff;
                const float4 y4 = *(const float4*)&ytile[tp2 * NCHF + (((lg + tp2) & 7) << 2)];
                acc[0][0] += wv * y4.x; acc[0][1] += wv * y4.y;
                acc[0][2] += wv * y4.z; acc[0][3] += wv * y4.w;
            }
            {
                float wv = live ? (d1[0] + bv) : 0.f;
                int tp2 = pb1 + tapoff;
                const float4 y4 = *(const float4*)&ytile[tp2 * NCHF + (((lg + tp2) & 7) << 2)];
                acc[1][0] += wv * y4.x; acc[1][1] += wv * y4.y;
                acc[1][2] += wv * y4.z; acc[1][3] += wv * y4.w;
            }
            {
                float wv = live ? (d2[0] + bv) : 0.f;
                int tp2 = pb2 + tapoff;
                const float4 y4 = *(const float4*)&ytile[tp2 * NCHF + (((lg + tp2) & 7) << 2)];
                acc[2][0] += wv * y4.x; acc[2][1] += wv * y4.y;
                acc[2][2] += wv * y4.z; acc[2][3] += wv * y4.w;
            }
            {
                float wv = live ? (d3[0] + bv) : 0.f;
                int tp2 = pb3 + tapoff;
                const float4 y4 = *(const float4*)&ytile[tp2 * NCHF + (((lg + tp2) & 7) << 2)];
                acc[3][0] += wv * y4.x; acc[3][1] += wv * y4.y;
                acc[3][2] += wv * y4.z; acc[3][3] += wv * y4.w;
            }
        }

        #pragma unroll
        for (int nt = 0; nt < 4; ++nt)
            #pragma unroll
            for (int c = 0; c < 4; ++c) {
                float v = acc[nt][c];
                v += __shfl_xor(v, 16);
                v += __shfl_xor(v, 32);
                acc[nt][c] = v;
            }

        size_t ob = ((size_t)(b * C64 + g * GC4) << 14) + pix;
        #pragma unroll
        for (int c = 0; c < 4; ++c) {
            float s0 = (q & 1) ? acc[1][c] : acc[0][c];
            float s1 = (q & 1) ? acc[3][c] : acc[2][c];
            float vv = (q & 2) ? s1 : s0;
            out[ob + ((size_t)c << 14)] = vv;
        }
    }
}

extern "C" void kernel_launch(void* const* d_in, const int* in_sizes, int n_in,
                              void* d_out, int out_size, void* d_ws, size_t ws_size,
                              hipStream_t stream) {
    const float* x   = (const float*)d_in[0];
    const float* y   = (const float*)d_in[1];
    const float* w1  = (const float*)d_in[2];
    const float* b1  = (const float*)d_in[3];
    const float* gma = (const float*)d_in[4];
    const float* bta = (const float*)d_in[5];
    const float* mu  = (const float*)d_in[6];
    const float* var = (const float*)d_in[7];
    const float* w2  = (const float*)d_in[8];
    const float* b2  = (const float*)d_in[9];
    float* out = (float*)d_out;

    const size_t t_bytes = (size_t)4 * 16384 * 32 * sizeof(_Float16);  // 4 MB
    if (ws_size >= t_bytes) {
        _Float16* t = (_Float16*)d_ws;
        hipLaunchKernelGGL(conv1_bn_relu, dim3(1024), dim3(256), 0, stream,
                           x, w1, b1, gma, bta, mu, var, t);
        hipLaunchKernelGGL(invol_agg, dim3(16, 16, 16), dim3(256), 0, stream,
                           y, t, w2, b2, out);
    } else {
        hipLaunchKernelGGL(involution_fused_fb, dim3(16, 16, 8), dim3(256), 0, stream,
                           x, y, w1, b1, gma, bta, mu, var, w2, b2, out);
    }
}